// Round 10
// baseline (231.447 us; speedup 1.0000x reference)
//
#include <hip/hip_runtime.h>
#include <stdint.h>
#include <stddef.h>

#define DIM   256
#define NH    8
#define HD    32
#define BATCH 16
#define NTOK  4096   // 64*64

typedef __attribute__((ext_vector_type(8))) short short8;
typedef __attribute__((ext_vector_type(4))) float f32x4;

__device__ __forceinline__ unsigned short f2bf(float x){
  unsigned u = __float_as_uint(x);
  u += 0x7fffu + ((u >> 16) & 1u);       // RNE
  return (unsigned short)(u >> 16);
}
__device__ __forceinline__ float elu1(float v){
  return (v > 0.f) ? (v + 1.f) : __expf(v);
}
// async global->LDS, 16B per lane. lds dest = wave-uniform base + lane*16.
__device__ __forceinline__ void gload_lds16(const void* g, void* lds){
  __builtin_amdgcn_global_load_lds(
      (const __attribute__((address_space(1))) unsigned int*)g,
      (__attribute__((address_space(3))) unsigned int*)lds, 16, 0, 0);
}

// ---------------- P1+P2 merged: transpose x AND convert Wqkv in one launch ----------------
__global__ __launch_bounds__(256) void k_prep(const float* __restrict__ x,
                                              unsigned short* __restrict__ xt,
                                              const float* __restrict__ wqkv,
                                              unsigned short* __restrict__ wq_bf){
  const int t = threadIdx.x;
  if (blockIdx.z < 16){
    __shared__ float tile[64][65];
    const int b = blockIdx.z, c0 = blockIdx.y * 64, n0 = blockIdx.x * 64;
    const float* xb = x + (size_t)b * DIM * NTOK;
    #pragma unroll
    for (int p = 0; p < 4; p++){
      int idx = t + p * 256;
      int row = idx >> 4;
      int col = (idx & 15) << 2;
      float4 v = *(const float4*)(xb + (size_t)(c0 + row) * NTOK + n0 + col);
      tile[row][col] = v.x; tile[row][col+1] = v.y; tile[row][col+2] = v.z; tile[row][col+3] = v.w;
    }
    __syncthreads();
    unsigned short* xtb = xt + (size_t)b * NTOK * DIM;
    #pragma unroll
    for (int p = 0; p < 4; p++){
      int idx = t + p * 256;
      int nl = idx >> 4;
      int cl = (idx & 15) << 2;
      ushort4 o;
      o.x = f2bf(tile[cl+0][nl]); o.y = f2bf(tile[cl+1][nl]);
      o.z = f2bf(tile[cl+2][nl]); o.w = f2bf(tile[cl+3][nl]);
      *(ushort4*)(xtb + (size_t)(n0 + nl) * DIM + c0 + cl) = o;
    }
  } else {
    const int blk = blockIdx.y * 64 + blockIdx.x;   // 0..255, use first 192
    if (blk >= 192) return;
    int i = blk * 256 + t;            // 49152 threads: 768 rows x 64 groups of 4c
    int row = i >> 6;
    int c4 = (i & 63) * 4;
    int dst;
    if (row < 256)      dst = row;
    else if (row < 512){ int p = (row - 256) >> 6; int s = (row - 256) & 63; dst = 256 + p*128 + s; }
    else               { int p = (row - 512) >> 6; int s = (row - 512) & 63; dst = 256 + p*128 + 64 + s; }
    float4 v = *(const float4*)(wqkv + (size_t)row * DIM + c4);
    ushort4 o = { f2bf(v.x), f2bf(v.y), f2bf(v.z), f2bf(v.w) };
    *(ushort4*)(wq_bf + (size_t)dst * DIM + c4) = o;
  }
}

// per-step staging for 256o x 128n tile: wave w stages 4 A slabs + 2 B slabs (6 gloads/thread).
// A: 32 slabs (16 row-groups x 2 k-halves); B: 16 slabs (8 x 2). slab = 16 rows x 32 k = 512 u16.
__device__ __forceinline__ void stage13(const unsigned short* __restrict__ A,
                                        const unsigned short* __restrict__ B,
                                        unsigned short* buf, int k0,
                                        int w, int t16, int quad){
  #pragma unroll
  for (int c = 0; c < 4; c++){
    int s = w*4 + c;                 // A slab 0..31
    int f = s >> 1, kk = s & 1;
    gload_lds16(A + (size_t)(f*16 + t16) * DIM + k0 + kk*32 + quad*8, buf + s*512);
  }
  #pragma unroll
  for (int c = 0; c < 2; c++){
    int s = w*2 + c;                 // B slab 0..15
    int f = s >> 1, kk = s & 1;
    gload_lds16(B + (size_t)(f*16 + t16) * DIM + k0 + kk*32 + quad*8, buf + 16384 + s*512);
  }
}

// ---------------- K1: qkv GEMM, 256o x 128n tile, 32 MFMA/wave per barrier-pair, no spill ----------------
// 1536 blocks = 3 o-tiles x 512 chunks (b,nt128). tile0 = q; tile1/2 = two k|v head-pairs each.
// K=256 in 4 steps of 64; 2x48KB LDS dbuf; counted vmcnt(6); single fused epilogue reusing LDS.
// acc[8][2]=64 regs + av 32 + bv 8 => fits the 256-reg cap at 1 block/CU, zero scratch.
// R9 fix: q-path qn store now covers all 32 o-chunks (was 16 -> half the tile never written).
__global__ __launch_bounds__(512, 1) void k_qkv13(const unsigned short* __restrict__ wbf,
                                                  const unsigned short* __restrict__ xt,
                                                  unsigned short* __restrict__ qn,
                                                  float* __restrict__ kvp){
  __shared__ __align__(16) unsigned short sh[49152];  // 2 x 24576 u16 staging; epilogue bounce reuse
  const int t = threadIdx.x;
  const int w = t >> 6, l = t & 63;
  const int t16 = l & 15, quad = l >> 4;
  const int wm = w >> 2, wn = w & 3;     // wm 0..1 (o-half 128), wn 0..3 (n-quarter 32)
  // swizzle: 3 o-tiles of one chunk inside a 24-bid window
  const int bid = blockIdx.x;
  const int super = bid / 24;            // 0..63
  const int rem = bid - super * 24;
  const int m = rem >> 3, lx = rem & 7;  // m 0..2
  const int chunk = super * 8 + lx;      // 0..511
  const int b = chunk >> 5, nt = chunk & 31;
  const int o0 = m * 256, n0 = nt * 128;
  const bool isQ = (m == 0);
  const unsigned short* A = wbf + (size_t)o0 * DIM;
  const unsigned short* B = xt + ((size_t)b * NTOK + n0) * DIM;

  stage13(A, B, sh,         0,  w, t16, quad);   // step 0 -> buf0
  stage13(A, B, sh + 24576, 64, w, t16, quad);   // step 1 -> buf1

  f32x4 acc[8][2];   // i over o (8x16), j over n (2x16)
  #pragma unroll
  for (int i = 0; i < 8; i++)
    #pragma unroll
    for (int j = 0; j < 2; j++){ acc[i][j][0]=0.f; acc[i][j][1]=0.f; acc[i][j][2]=0.f; acc[i][j][3]=0.f; }

  #pragma unroll
  for (int s = 0; s < 4; s++){
    if (s < 3) { asm volatile("s_waitcnt vmcnt(6)" ::: "memory"); }
    else       { asm volatile("s_waitcnt vmcnt(0)" ::: "memory"); }
    __builtin_amdgcn_s_barrier();                   // all waves' stage(s) complete
    const unsigned short* buf = sh + (s & 1) * 24576;
    #pragma unroll
    for (int kk = 0; kk < 2; kk++){
      short8 av[8], bv[2];
      #pragma unroll
      for (int i = 0; i < 8; i++) av[i] = *(const short8*)(buf + ((wm*8 + i)*2 + kk)*512 + l*8);
      #pragma unroll
      for (int j = 0; j < 2; j++) bv[j] = *(const short8*)(buf + 16384 + ((wn*2 + j)*2 + kk)*512 + l*8);
      #pragma unroll
      for (int i = 0; i < 8; i++)
        #pragma unroll
        for (int j = 0; j < 2; j++)
          acc[i][j] = __builtin_amdgcn_mfma_f32_16x16x32_bf16(av[i], bv[j], acc[i][j], 0, 0, 0);
    }
    __builtin_amdgcn_s_barrier();                   // all waves consumed buf[s&1]
    if (s < 2) stage13(A, B, sh + (s & 1)*24576, (s + 2)*64, w, t16, quad);
  }
  unsigned short* bsh = sh;   // epilogue bounce reuses staging LDS

  if (isQ){
    // elu + per-head (32 o-rows) normalize on all 8 o-frags
    #pragma unroll
    for (int i = 0; i < 8; i++)
      #pragma unroll
      for (int j = 0; j < 2; j++)
        #pragma unroll
        for (int r = 0; r < 4; r++) acc[i][j][r] = elu1(acc[i][j][r]);
    #pragma unroll
    for (int hh = 0; hh < 4; hh++)
      #pragma unroll
      for (int j = 0; j < 2; j++){
        float v = 0.f;
        #pragma unroll
        for (int ii = 0; ii < 2; ii++)
          #pragma unroll
          for (int r = 0; r < 4; r++) v += acc[hh*2 + ii][j][r];
        v += __shfl_xor(v, 16);
        v += __shfl_xor(v, 32);
        float inv = 1.0f / v;
        #pragma unroll
        for (int ii = 0; ii < 2; ii++)
          #pragma unroll
          for (int r = 0; r < 4; r++) acc[hh*2 + ii][j][r] *= inv;
      }
    // bounce [n 128][o stride 264], packed ushort4 along o
    #pragma unroll
    for (int i = 0; i < 8; i++)
      #pragma unroll
      for (int j = 0; j < 2; j++){
        int n_l = wn*32 + j*16 + t16;
        int o_l0 = wm*128 + i*16 + quad*4;
        ushort4 pk = { f2bf(acc[i][j][0]), f2bf(acc[i][j][1]),
                       f2bf(acc[i][j][2]), f2bf(acc[i][j][3]) };
        *(ushort4*)(bsh + n_l*264 + o_l0) = pk;
      }
    asm volatile("s_waitcnt lgkmcnt(0)" ::: "memory");
    __builtin_amdgcn_s_barrier();
    unsigned short* dst = qn + (size_t)b * NTOK * DIM;
    #pragma unroll
    for (int p2 = 0; p2 < 8; p2++){
      int idx = t + p2 * 512;          // 4096 16B-chunks: 128 n x 32 chunks (FULL 256 o)
      int n_l = idx >> 5, c16 = idx & 31;
      uint4 v = *(const uint4*)(bsh + n_l*264 + c16*8);
      *(uint4*)(dst + (size_t)(n0 + n_l) * DIM + c16*8) = v;
    }
  } else {
    // k rows = frags i 0..3 of the wave's pair (wm): elu + normalize per head (hh 0..1)
    #pragma unroll
    for (int i = 0; i < 4; i++)
      #pragma unroll
      for (int j = 0; j < 2; j++)
        #pragma unroll
        for (int r = 0; r < 4; r++) acc[i][j][r] = elu1(acc[i][j][r]);
    #pragma unroll
    for (int hh = 0; hh < 2; hh++)
      #pragma unroll
      for (int j = 0; j < 2; j++){
        float v = 0.f;
        #pragma unroll
        for (int ii = 0; ii < 2; ii++)
          #pragma unroll
          for (int r = 0; r < 4; r++) v += acc[hh*2 + ii][j][r];
        v += __shfl_xor(v, 16);
        v += __shfl_xor(v, 32);
        float inv = 1.0f / v;
        #pragma unroll
        for (int ii = 0; ii < 2; ii++)
          #pragma unroll
          for (int r = 0; r < 4; r++) acc[hh*2 + ii][j][r] *= inv;
      }
    // bounce [o 256][n stride 136] (n-contiguous rows for kv MFMA)
    #pragma unroll
    for (int i = 0; i < 8; i++)
      #pragma unroll
      for (int j = 0; j < 2; j++){
        int n_l = wn*32 + j*16 + t16;
        #pragma unroll
        for (int r = 0; r < 4; r++){
          int o_l = wm*128 + i*16 + quad*4 + r;
          bsh[o_l*136 + n_l] = f2bf(acc[i][j][r]);
        }
      }
    asm volatile("s_waitcnt lgkmcnt(0)" ::: "memory");
    __builtin_amdgcn_s_barrier();
    // kv partials over 128 tokens: 16 tasks (pair q, hl, dh, eh); wave w does tasks w, w+8
    #pragma unroll
    for (int task = 0; task < 2; task++){
      const int tt = w + task*8;
      const int q = tt >> 3, hl = (tt >> 2) & 1, dh = (tt >> 1) & 1, eh = tt & 1;
      f32x4 kvacc;
      kvacc[0]=0.f; kvacc[1]=0.f; kvacc[2]=0.f; kvacc[3]=0.f;
      const unsigned short* kbase = bsh + (q*128 + hl*32 + dh*16 + t16) * 136;       // normalized k
      const unsigned short* vbase = bsh + (q*128 + 64 + hl*32 + eh*16 + t16) * 136;  // raw v
      #pragma unroll
      for (int kk2 = 0; kk2 < 4; kk2++){
        int nn = kk2*32 + quad*8;
        short8 afrag = *(const short8*)(kbase + nn);
        short8 bfrag = *(const short8*)(vbase + nn);
        kvacc = __builtin_amdgcn_mfma_f32_16x16x32_bf16(afrag, bfrag, kvacc, 0, 0, 0);
      }
      const int pp_g = (m - 1)*2 + q;   // global head-pair 0..3
      float* dst = kvp + ((size_t)((b*8 + pp_g*2 + hl) * 32 + nt)) * 1024;
      #pragma unroll
      for (int r = 0; r < 4; r++)
        dst[(dh*16 + quad*4 + r)*32 + eh*16 + t16] = kvacc[r];
    }
  }
}

// ---------------- K3: reduce kv partials (32) + fold Wproj ----------------
__global__ __launch_bounds__(256) void k_M(const float* __restrict__ kvp,
                                           const float* __restrict__ wproj,
                                           unsigned short* __restrict__ M){
  __shared__ float kvL[1024];
  __shared__ float wpL[8192];   // [o][e] 256x32
  const int t = threadIdx.x;
  const int h = blockIdx.x, b = blockIdx.y;
  const float* pbase = kvp + (size_t)((b*8 + h) * 32) * 1024;
  {
    float4 a = {0.f,0.f,0.f,0.f};
    #pragma unroll
    for (int p = 0; p < 32; p++){
      float4 v = *(const float4*)(pbase + (size_t)p*1024 + t*4);
      a.x += v.x; a.y += v.y; a.z += v.z; a.w += v.w;
    }
    *(float4*)(kvL + t*4) = a;
  }
  #pragma unroll
  for (int p = 0; p < 8; p++){
    int idx = t + p * 256;          // float4 index over 256x32
    int o = idx >> 3, e4 = idx & 7;
    *(float4*)(wpL + o*32 + e4*4) = *(const float4*)(wproj + (size_t)o * DIM + h*32 + e4*4);
  }
  __syncthreads();
  float wr[32];
  #pragma unroll
  for (int e = 0; e < 32; e++) wr[e] = wpL[t*32 + e];
  unsigned short md[32];
  #pragma unroll
  for (int d = 0; d < 32; d++){
    float a = 0.f;
    #pragma unroll
    for (int e = 0; e < 32; e++) a += wr[e] * kvL[d*32 + e];
    md[d] = f2bf(a);
  }
  unsigned short* dst = M + (size_t)b * 65536 + (size_t)t * DIM + h*32;
  #pragma unroll
  for (int q = 0; q < 4; q++) *(uint4*)(dst + q*8) = *(const uint4*)(md + q*8);
}

// ---------------- K4: out GEMM, 128o x 256n tile (512 blocks), FLIPPED operands ----------------
__global__ __launch_bounds__(512, 2) void k_out6(const unsigned short* __restrict__ M,
                                                 const unsigned short* __restrict__ qn,
                                                 const float* __restrict__ x,
                                                 const float* __restrict__ bproj,
                                                 float* __restrict__ out){
  __shared__ __align__(16) unsigned short As[16384];  // qn: 256n x 64k (32 slabs)
  __shared__ __align__(16) unsigned short Bs[8192];   // M : 128o x 64k (16 slabs)
  const int t = threadIdx.x;
  const int w = t >> 6, l = t & 63;
  const int t16 = l & 15, quad = l >> 4;
  const int wm = w >> 1, wn = w & 1;     // wm 0..3: n-quarter, wn 0..1: o-half
  const int bid = blockIdx.x;
  const int super = bid >> 4;            // 0..31
  const int rem = bid & 15;
  const int m = rem >> 3, lx = rem & 7;
  const int g = super * 8 + lx;          // 0..255
  const int nt = g >> 4, b = g & 15;
  const int o0 = m * 128, n0 = nt * 256;
  const unsigned short* A = qn + (size_t)b * NTOK * DIM;  // [n][256]
  const unsigned short* Bm = M + (size_t)b * 65536;       // [256][256]

  f32x4 acc[4][4];   // i over n (4x16), j over o (4x16)
  #pragma unroll
  for (int i = 0; i < 4; i++)
    #pragma unroll
    for (int j = 0; j < 4; j++){ acc[i][j][0]=0.f; acc[i][j][1]=0.f; acc[i][j][2]=0.f; acc[i][j][3]=0.f; }

  for (int k0 = 0; k0 < 256; k0 += 64){
    __syncthreads();
    #pragma unroll
    for (int s4 = 0; s4 < 4; s4++){
      int sl = w*4 + s4;               // 0..31
      int tile = sl >> 1, kk = sl & 1;
      gload_lds16(A + (size_t)(n0 + tile*16 + t16) * DIM + k0 + kk*32 + quad*8, As + sl*512);
    }
    #pragma unroll
    for (int s2 = 0; s2 < 2; s2++){
      int sl = w*2 + s2;               // 0..15
      int tile = sl >> 1, kk = sl & 1;
      gload_lds16(Bm + (size_t)(o0 + tile*16 + t16) * DIM + k0 + kk*32 + quad*8, Bs + sl*512);
    }
    __syncthreads();
    #pragma unroll
    for (int kk = 0; kk < 2; kk++){
      short8 a[4], bb[4];
      #pragma unroll
      for (int i = 0; i < 4; i++) a[i]  = *(const short8*)(As + ((wm*4 + i)*2 + kk) * 512 + l * 8);
      #pragma unroll
      for (int j = 0; j < 4; j++) bb[j] = *(const short8*)(Bs + ((wn*4 + j)*2 + kk) * 512 + l * 8);
      #pragma unroll
      for (int i = 0; i < 4; i++)
        #pragma unroll
        for (int j = 0; j < 4; j++)
          acc[i][j] = __builtin_amdgcn_mfma_f32_16x16x32_bf16(a[i], bb[j], acc[i][j], 0, 0, 0);
    }
  }

  const float* xb = x + (size_t)b * DIM * NTOK;
  float* ob = out + (size_t)b * DIM * NTOK;
  #pragma unroll
  for (int j = 0; j < 4; j++){
    int o = o0 + wn*64 + j*16 + t16;
    float bias = bproj[o];
    #pragma unroll
    for (int i = 0; i < 4; i++){
      int n = n0 + wm*64 + i*16 + quad*4;
      float4 xv = *(const float4*)(xb + (size_t)o * NTOK + n);
      float4 res = { acc[i][j][0] + bias + xv.x,
                     acc[i][j][1] + bias + xv.y,
                     acc[i][j][2] + bias + xv.z,
                     acc[i][j][3] + bias + xv.w };
      *(float4*)(ob + (size_t)o * NTOK + n) = res;
    }
  }
}

extern "C" void kernel_launch(void* const* d_in, const int* in_sizes, int n_in,
                              void* d_out, int out_size, void* d_ws, size_t ws_size,
                              hipStream_t stream){
  const float* x     = (const float*)d_in[0];
  const float* wqkv  = (const float*)d_in[1];
  const float* wproj = (const float*)d_in[2];
  const float* bproj = (const float*)d_in[3];
  float* out = (float*)d_out;
  char* ws = (char*)d_ws;

  // ws layout:
  unsigned short* xt   = (unsigned short*)(ws);                        // 32 MiB [b][n][256]
  unsigned short* qn   = (unsigned short*)(ws + ((size_t)32 << 20));   // 32 MiB [b][n][256]
  float* kvp           = (float*)(ws + ((size_t)64 << 20));            // 16 MiB [b][h][nt 32][1024]
  unsigned short* M    = (unsigned short*)(ws + ((size_t)80 << 20));   // 2 MiB [b][256][256]
  unsigned short* wqbf = (unsigned short*)(ws + ((size_t)82 << 20));   // 384 KiB permuted

  k_prep  <<<dim3(64, 4, 17), 256, 0, stream>>>(x, xt, wqkv, wqbf);
  k_qkv13 <<<dim3(1536), 512, 0, stream>>>(wqbf, xt, qn, kvp);
  k_M     <<<dim3(8, 16), 256, 0, stream>>>(kvp, wproj, M);
  k_out6  <<<dim3(512), 512, 0, stream>>>(M, qn, x, bproj, out);
}